// Round 7
// baseline (584.014 us; speedup 1.0000x reference)
//
#include <hip/hip_runtime.h>
#include <hip/hip_cooperative_groups.h>
#include <hip/hip_bf16.h>

namespace cg = cooperative_groups;
typedef __hip_bfloat16 bf16;

constexpr int CB = 8;     // batch
constexpr int CT = 512;   // T
constexpr int CN = 64;    // N
constexpr int CD = 128;   // D
constexpr int CP = 96;    // PRED
constexpr int CH = 8;     // HEADS
constexpr int CDH = 16;   // head dim
constexpr int CHID = 256; // HID
constexpr int CM = 32;    // CEM freq tokens
constexpr int CG = 64;    // TEM freq tokens
constexpr float TWO_PI = 6.28318530717958647692f;

__device__ __forceinline__ float LD(const void* p, size_t i, bool f) {
  return f ? ((const float*)p)[i] : __bfloat162float(((const bf16*)p)[i]);
}
template <bool F32>
__device__ __forceinline__ float LDT(const void* p, size_t i) {
  return F32 ? ((const float*)p)[i] : __bfloat162float(((const bf16*)p)[i]);
}

__device__ __forceinline__ bool detect_f32(const void* x) {
  const unsigned int* xw = (const unsigned int*)x;
  unsigned int w = xw[threadIdx.x & 63];
  unsigned int e = (w >> 7) & 0xFF;
  unsigned long long m = __ballot(e >= 0x90 || e <= 0x60);
  return __popcll(m) > 3;
}

__device__ __forceinline__ float2 pkfma(float2 a, float2 b, float2 c) {
  return make_float2(fmaf(a.x, b.x, c.x), fmaf(a.y, b.y, c.y));
}

struct MArgs {
  const void *x, *dec_w, *dec_b, *out_w, *emb, *cWq, *cWk, *cWv, *cWo;
  const void *tWq, *tWk, *tWv, *tWo, *drw, *drb, *out_b, *wfuse;
  const void *w1, *b1, *w2, *b2, *w3, *b3;
  float *res, *trend, *trendo, *Pbuf, *Qbuf, *ch, *ewo, *ewq, *ewk, *ewv, *wod;
  float *owr, *owi, *gC, *gU;
  void* out;
};

// ======================= STAGE 1: k1 [0,32) | k_ow [32,96) | k0a [96] =======================
__device__ void stage1(const MArgs& a, float* sm, bool f32, int blk, int tid) {
  if (blk < 32) {
    // k1: decomposition; sliding-window moving averages (4 LDS reads/step)
    float* xl = sm; // [512][16]
    int b = blk >> 2, n0 = (blk & 3) * 16;
    size_t base = (size_t)b * CT * CN + n0;
    for (int i = tid; i < CT * 16; i += 256) {
      int t = i >> 4, j = i & 15;
      xl[t * 16 + j] = LD(a.x, base + (size_t)t * CN + j, f32);
    }
    __syncthreads();
    float w0 = LD(a.dec_w, 0, f32), w1 = LD(a.dec_w, 1, f32);
    float c0 = LD(a.dec_b, 0, f32), c1 = LD(a.dec_b, 1, f32);
    int j = tid & 15, tl = tid >> 4;
    int t0 = tl * 32;
    float s17 = 0.f, s49 = 0.f;
    #pragma unroll
    for (int o = -8; o <= 8; ++o) {
      int u = t0 + o; u = u < 0 ? 0 : (u > CT - 1 ? CT - 1 : u);
      s17 += xl[u * 16 + j];
    }
    #pragma unroll
    for (int o = -24; o <= 24; ++o) {
      int u = t0 + o; u = u < 0 ? 0 : (u > CT - 1 ? CT - 1 : u);
      s49 += xl[u * 16 + j];
    }
    for (int k = 0; k < 32; ++k) {
      int t = t0 + k;
      if (k > 0) {
        int up8 = t + 8 > CT - 1 ? CT - 1 : t + 8;
        int dn9 = t - 9 < 0 ? 0 : t - 9;
        int up24 = t + 24 > CT - 1 ? CT - 1 : t + 24;
        int dn25 = t - 25 < 0 ? 0 : t - 25;
        s17 += xl[up8 * 16 + j] - xl[dn9 * 16 + j];
        s49 += xl[up24 * 16 + j] - xl[dn25 * 16 + j];
      }
      float m0 = s17 * (1.f / 17.f), m1 = s49 * (1.f / 49.f);
      float xv = xl[t * 16 + j];
      float l0 = xv * w0 + c0, l1 = xv * w1 + c1;
      float mx = fmaxf(l0, l1);
      float e0 = __expf(l0 - mx), e1 = __expf(l1 - mx);
      float tr = (e0 * m0 + e1 * m1) / (e0 + e1);
      size_t o = ((size_t)(b * CT + t)) * CN + n0 + j;
      a.trend[o] = tr;
      a.res[o] = xv - tr;
    }
  } else if (blk < 96) {
    // k_ow: phasor recurrence, 2 t-halves per block, LDS partial reduce
    float* ps = sm; // [2][96][2]
    int g = blk - 32;
    int tc = tid >> 7, idx = tid & 127;
    if (idx < CP) {
      int p = idx, t0 = tc * 256;
      float s0, c0v, ss, cs;
      sincosf((float)((g * t0) & (CT - 1)) * (TWO_PI / CT), &s0, &c0v);
      sincosf((float)g * (TWO_PI / CT), &ss, &cs);
      float wr = c0v, wi = s0, ar = 0.f, ai = 0.f;
      #pragma unroll 16
      for (int t = 0; t < 256; ++t) {
        float w = LD(a.out_w, (size_t)(t0 + t) * CP + p, f32);
        ar = fmaf(w, wr, ar); ai = fmaf(w, wi, ai);
        float nr = wr * cs - wi * ss; wi = wi * cs + wr * ss; wr = nr;
      }
      ps[(tc * CP + p) * 2] = ar; ps[(tc * CP + p) * 2 + 1] = ai;
    }
    __syncthreads();
    if (tid < CP) {
      a.owr[g * CP + tid] = ps[tid * 2] + ps[(CP + tid) * 2];
      a.owi[g * CP + tid] = ps[tid * 2 + 1] + ps[(CP + tid) * 2 + 1];
    }
  } else if (blk == 96) {
    // k0a: emb projections, ch, wod, ewo
    float* eml = sm; float* drl = sm + 128; float* eql = sm + 256;
    float* ekl = sm + 384; float* evl = sm + 512;
    if (tid < 128) eml[tid] = LD(a.emb, tid, f32);
    else drl[tid - 128] = LD(a.drw, tid - 128, f32);
    __syncthreads();
    int e = tid & 127;
    for (int pass = 0; pass < 2; ++pass) {
      int grp = pass * 2 + (tid >> 7);
      if (grp < 3) {
        const void* W = grp == 0 ? a.cWq : (grp == 1 ? a.cWk : a.cWv);
        float acc = 0;
        #pragma unroll 16
        for (int d = 0; d < CD; ++d) acc += eml[d] * LD(W, d * CD + e, f32);
        (grp == 0 ? eql : (grp == 1 ? ekl : evl))[e] = acc;
      } else {
        float acc = 0;
        #pragma unroll 16
        for (int d = 0; d < CD; ++d) acc += LD(a.tWo, e * CD + d, f32) * drl[d];
        a.wod[e] = acc;
      }
    }
    __syncthreads();
    if (tid < CH) {
      float c = 0;
      for (int j = 0; j < CDH; ++j) c += eql[tid * CDH + j] * ekl[tid * CDH + j];
      a.ch[tid] = fabsf(c);
    }
    int half = tid >> 7;
    for (int hh = 0; hh < 4; ++hh) {
      int h = half * 4 + hh;
      float acc = 0;
      #pragma unroll
      for (int j = 0; j < CDH; ++j)
        acc += evl[h * CDH + j] * LD(a.cWo, (h * CDH + j) * CD + e, f32);
      a.ewo[h * CD + e] = acc;
    }
  }
}

// ======================= STAGE 2: k2 [0,128) | k3 [128,1012) | k0b [1012,1024) ==============
template <bool F32>
__device__ void k2_body(float* sm, const MArgs& a) {
  float* rows = sm;          // [4][512]
  float* h1 = sm + 2048;     // [4][256]
  float* h2 = sm + 3072;     // [4][256]
  int r0 = blockIdx.x * 4;
  int b = r0 >> 6, n0 = r0 & 63;
  int tid = threadIdx.x;
  const float* tb = a.trend + (size_t)b * CT * CN + n0;
  for (int i = tid; i < 4 * CT; i += 256) {
    int q = i & 3, t = i >> 2;
    rows[q * CT + t] = tb[(size_t)t * CN + q];
  }
  __syncthreads();
  int c = tid;
  float a0, a1, a2, a3;
  {
    float bias = LDT<F32>(a.b1, c);
    a0 = a1 = a2 = a3 = 0.f;
    #pragma unroll 16
    for (int t = 0; t < CT; ++t) {
      float w = LDT<F32>(a.w1, t * CHID + c);
      a0 += rows[0 * CT + t] * w; a1 += rows[1 * CT + t] * w;
      a2 += rows[2 * CT + t] * w; a3 += rows[3 * CT + t] * w;
    }
    h1[0 * CHID + c] = fmaxf(a0 + bias, 0.f); h1[1 * CHID + c] = fmaxf(a1 + bias, 0.f);
    h1[2 * CHID + c] = fmaxf(a2 + bias, 0.f); h1[3 * CHID + c] = fmaxf(a3 + bias, 0.f);
  }
  __syncthreads();
  {
    float bias = LDT<F32>(a.b2, c);
    a0 = a1 = a2 = a3 = 0.f;
    #pragma unroll 16
    for (int i = 0; i < CHID; ++i) {
      float w = LDT<F32>(a.w2, i * CHID + c);
      a0 += h1[0 * CHID + i] * w; a1 += h1[1 * CHID + i] * w;
      a2 += h1[2 * CHID + i] * w; a3 += h1[3 * CHID + i] * w;
    }
    h2[0 * CHID + c] = fmaxf(a0 + bias, 0.f); h2[1 * CHID + c] = fmaxf(a1 + bias, 0.f);
    h2[2 * CHID + c] = fmaxf(a2 + bias, 0.f); h2[3 * CHID + c] = fmaxf(a3 + bias, 0.f);
  }
  __syncthreads();
  if (tid < 2 * CP) {
    int p = tid < CP ? tid : tid - CP;
    int qh = tid < CP ? 0 : 2;
    float bias = LDT<F32>(a.b3, p);
    a0 = a1 = 0.f;
    #pragma unroll 16
    for (int i = 0; i < CHID; ++i) {
      float w = LDT<F32>(a.w3, i * CP + p);
      a0 += h2[qh * CHID + i] * w; a1 += h2[(qh + 1) * CHID + i] * w;
    }
    a.trendo[((size_t)(b * CN + n0 + qh)) * CP + p] = a0 + bias;
    a.trendo[((size_t)(b * CN + n0 + qh + 1)) * CP + p] = a1 + bias;
  }
}

__device__ void stage2(const MArgs& a, float* sm, bool f32, int blk, int tid) {
  if (blk < 128) {
    if (f32) k2_body<true>(sm, a);
    else     k2_body<false>(sm, a);
  } else if (blk < 1012) {
    // k3: CEM collapsed attention; 4 waves/block, uniform trip count per block
    float* rowl = sm;            // [4][64]
    float* twc = sm + 256;       // [64]
    float* tws = sm + 320;       // [64]
    float* chl = sm + 384;       // [8]
    float* Rr = sm + 392;        // [4][32]
    float* Ri = sm + 520;
    float* aR = sm + 648;
    float* Sr = sm + 776;        // [4][256]
    float* Si = sm + 1800;
    int bk = blk - 128;
    int iters = bk < 140 ? 2 : 1;
    int tbase = bk < 140 ? bk * 8 : 140 * 8 + (bk - 140) * 4;
    int w = tid >> 6, lane = tid & 63;
    if (w == 0) {
      float s, c;
      sincosf((float)lane * (TWO_PI / CN), &s, &c);
      twc[lane] = c; tws[lane] = s;
    }
    if (tid < CH) chl[tid] = a.ch[tid];
    __syncthreads();
    for (int it = 0; it < iters; ++it) {
      int task = tbase + it * 4 + w;
      int b = task >> 9, t = task & 511;
      rowl[w * 64 + lane] = a.res[((size_t)(b * CT + t)) * CN + lane];
      __syncthreads();
      if (lane < CM) {
        float rr = 0, ri = 0;
        int idx = 0;
        for (int n2 = 0; n2 < CN; ++n2) {
          rr += rowl[w * 64 + n2] * twc[idx];
          ri -= rowl[w * 64 + n2] * tws[idx];
          idx = (idx + lane) & (CN - 1);
        }
        Rr[w * 32 + lane] = rr; Ri[w * 32 + lane] = ri;
        aR[w * 32 + lane] = sqrtf(rr * rr + ri * ri);
      }
      __syncthreads();
      float amax = 0;
      for (int m = 0; m < CM; ++m) amax = fmaxf(amax, aR[w * 32 + m]);
      for (int i = 0; i < 4; ++i) {
        int pair = lane + 64 * i;
        int h = pair >> 5, m = pair & 31;
        float alpha = 0.25f * chl[h] * aR[w * 32 + m];
        float den = 0, sr = 0, si = 0;
        for (int n2 = 0; n2 < CM; ++n2) {
          float e = __expf(alpha * (aR[w * 32 + n2] - amax));
          den += e; sr += e * Rr[w * 32 + n2]; si += e * Ri[w * 32 + n2];
        }
        Sr[w * 256 + pair] = sr / den; Si[w * 256 + pair] = si / den;
      }
      __syncthreads();
      int n2 = lane;
      float av[8];
      for (int h = 0; h < CH; ++h) {
        float acc = Sr[w * 256 + h * CM]; // f=0 (Re only; irfft drops bin-0 imag)
        int idx = n2 & (CN - 1);
        #pragma unroll
        for (int f = 1; f < CM; ++f) {
          acc += 2.f * (Sr[w * 256 + h * CM + f] * twc[idx]
                      - Si[w * 256 + h * CM + f] * tws[idx]);
          idx = (idx + n2) & (CN - 1);
        }
        av[h] = acc * (1.f / CN);
      }
      float* Pb = a.Pbuf + (((size_t)(b * CN + n2)) * CT + t) * CH;
      ((float4*)Pb)[0] = make_float4(av[0], av[1], av[2], av[3]);
      ((float4*)Pb)[1] = make_float4(av[4], av[5], av[6], av[7]);
      __syncthreads();
    }
  } else {
    // k0b: ewq/ewk/ewv = ewo @ tW{q,k,v}; 2 (which,h) pairs per block
    float* ew = sm; // [2][128]
    int pairIdx = (blk - 1012) * 2 + (tid >> 7);
    int which = pairIdx >> 3, h = pairIdx & 7, e = tid & 127;
    ew[(tid >> 7) * 128 + e] = a.ewo[h * CD + e];
    __syncthreads();
    const void* W = which == 0 ? a.tWq : (which == 1 ? a.tWk : a.tWv);
    float acc = 0;
    #pragma unroll 16
    for (int d = 0; d < CD; ++d) acc += ew[(tid >> 7) * 128 + d] * LD(W, d * CD + e, f32);
    (which == 0 ? a.ewq : (which == 1 ? a.ewk : a.ewv))[h * CD + e] = acc;
  }
}

// ======================= STAGE 3: k4 [0,512) | k0c [512] =======================
__device__ void stage3(const MArgs& a, float* sm, bool f32, int blk, int tid) {
  if (blk < 512) {
    float* Pl = sm; // [512][8]
    int b = blk >> 6, n = blk & 63;
    const float4* Pp4 = (const float4*)(a.Pbuf + ((size_t)(b * CN + n)) * CT * CH);
    float4* Pl4 = (float4*)Pl;
    for (int i = tid; i < CT * CH / 4; i += 256) Pl4[i] = Pp4[i];
    __syncthreads();
    int g1 = tid >> 3, h = tid & 7, g2 = g1 + 32;
    float s1, c1, s2, c2;
    sincosf((float)g1 * (TWO_PI / CT), &s1, &c1);
    sincosf((float)g2 * (TWO_PI / CT), &s2, &c2);
    float wr1 = 1.f, wi1 = 0.f, wr2 = 1.f, wi2 = 0.f;
    float r1 = 0, i1 = 0, r2 = 0, i2 = 0;
    #pragma unroll 8
    for (int t = 0; t < CT; ++t) {
      float p = Pl[t * CH + h];
      r1 += p * wr1; i1 += p * wi1;
      r2 += p * wr2; i2 += p * wi2;
      float nr1 = wr1 * c1 + wi1 * s1; wi1 = wi1 * c1 - wr1 * s1; wr1 = nr1;
      float nr2 = wr2 * c2 + wi2 * s2; wi2 = wi2 * c2 - wr2 * s2; wr2 = nr2;
    }
    float* Qb = a.Qbuf + ((size_t)(b * CN + n)) * CG * CH * 2;
    Qb[(g1 * CH + h) * 2] = r1; Qb[(g1 * CH + h) * 2 + 1] = i1;
    Qb[(g2 * CH + h) * 2] = r2; Qb[(g2 * CH + h) * 2 + 1] = i2;
  } else if (blk == 512) {
    for (int id = tid; id < 512 + 64; id += 256) {
      if (id < 512) {
        int h = id >> 6, aa = (id >> 3) & 7, b2 = id & 7;
        float c = 0;
        #pragma unroll
        for (int j = 0; j < CDH; ++j)
          c += a.ewq[aa * CD + h * CDH + j] * a.ewk[b2 * CD + h * CDH + j];
        a.gC[id] = c;
      } else {
        int r = id - 512;
        int h = r >> 3, aa = r & 7;
        float c = 0;
        #pragma unroll
        for (int j = 0; j < CDH; ++j) c += a.ewv[aa * CD + h * CDH + j] * a.wod[h * CDH + j];
        a.gU[r] = c;
      }
    }
  }
}

// ======================= STAGE 4: k5 on [0,512), 256 threads (4h x 64m, 2 hh iters) ========
__device__ void stage4(const MArgs& a, float* sm, bool f32, int blk, int tid) {
  if (blk >= 512) return;
  float* QL = sm;                         // [64][16]
  float* Cl = sm + 1024;                  // [512]
  float* Ul = sm + 1536;                  // [8][8]
  float2* vdL = (float2*)(sm + 1600);     // [8][64]
  float2* zL = (float2*)(sm + 2624);      // [8][64]
  float* zrow = sm + 3648;                // [64][2]
  int b = blk >> 6, n = blk & 63;
  const float* Qb = a.Qbuf + ((size_t)(b * CN + n)) * CG * CH * 2;
  for (int i = tid; i < 512; i += 256) ((float4*)QL)[i] = ((const float4*)Qb)[i];
  for (int i = tid; i < 512; i += 256) Cl[i] = a.gC[i];
  if (tid < 64) Ul[tid] = a.gU[tid];
  __syncthreads();
  int h0 = tid >> 6, m = tid & 63;
  float2 qp[8];
  {
    const float4* q4 = (const float4*)(QL + m * 16);
    #pragma unroll
    for (int j = 0; j < 4; ++j) {
      float4 y = q4[j];
      qp[2 * j] = make_float2(y.x, y.y);
      qp[2 * j + 1] = make_float2(y.z, y.w);
    }
  }
  #pragma unroll
  for (int e2 = 0; e2 < 2; ++e2) {
    int hh = h0 + e2 * 4;
    float vr = 0, vi = 0;
    #pragma unroll
    for (int aa = 0; aa < 8; ++aa) {
      float u = Ul[hh * 8 + aa];
      vr += qp[aa].x * u; vi += qp[aa].y * u;
    }
    vdL[hh * 64 + m] = make_float2(vr, vi);
  }
  __syncthreads();
  for (int e2 = 0; e2 < 2; ++e2) {
    int hh = h0 + e2 * 4;
    float2 uu[8], vv[8];
    #pragma unroll
    for (int bb = 0; bb < 8; ++bb) {
      float sr = 0, si = 0;
      #pragma unroll
      for (int aa = 0; aa < 8; ++aa) {
        float c = Cl[(hh * 8 + aa) * 8 + bb];
        sr += qp[aa].x * c; si += qp[aa].y * c;
      }
      uu[bb] = make_float2(sr, si);
      vv[bb] = make_float2(si, -sr);
    }
    float mx = -1e30f, den = 0.f, zr = 0.f, zi = 0.f;
    #pragma unroll 4
    for (int g = 0; g < CG; ++g) {
      const float4* k4p = (const float4*)(QL + g * 16);
      float2 sr2 = make_float2(0.f, 0.f), si2 = make_float2(0.f, 0.f);
      #pragma unroll
      for (int j = 0; j < 4; ++j) {
        float4 y = k4p[j];
        float2 y0 = make_float2(y.x, y.y), y1 = make_float2(y.z, y.w);
        sr2 = pkfma(uu[2 * j], y0, sr2); si2 = pkfma(vv[2 * j], y0, si2);
        sr2 = pkfma(uu[2 * j + 1], y1, sr2); si2 = pkfma(vv[2 * j + 1], y1, si2);
      }
      float sr = sr2.x + sr2.y;
      float si = si2.x + si2.y;
      float s = 0.25f * sqrtf(sr * sr + si * si);
      if (s > mx) {
        float f = __expf(mx - s);
        den *= f; zr *= f; zi *= f; mx = s;
      }
      float e = __expf(s - mx);
      float2 vd = vdL[hh * 64 + g];
      den += e; zr += e * vd.x; zi += e * vd.y;
    }
    float rv = 1.f / den;
    zL[hh * 64 + m] = make_float2(zr * rv, zi * rv);
  }
  __syncthreads();
  if (tid < 128) {
    int g = tid >> 1, c = tid & 1;
    float acc = 0;
    #pragma unroll
    for (int hh = 0; hh < CH; ++hh) acc += c ? zL[hh * 64 + g].y : zL[hh * 64 + g].x;
    zrow[g * 2 + c] = acc;
  }
  __syncthreads();
  if (tid < CP) {
    int p = tid;
    float acc = zrow[0] * a.owr[p] - zrow[1] * a.owi[p]; // g=0 (bin-0 imag dropped)
    #pragma unroll 8
    for (int g = 1; g < CG; ++g)
      acc += 2.f * (zrow[g * 2] * a.owr[g * CP + p] - zrow[g * 2 + 1] * a.owi[g * CP + p]);
    float xo = acc * (1.f / CT) + LD(a.drb, 0, f32) * a.owr[p] + LD(a.out_b, p, f32);
    float val = LD(a.wfuse, 0, f32) * xo
              + LD(a.wfuse, 1, f32) * a.trendo[((size_t)(b * CN + n)) * CP + p];
    size_t oidx = ((size_t)(b * CP + p)) * CN + n;
    if (f32) ((float*)a.out)[oidx] = val;
    else ((bf16*)a.out)[oidx] = __float2bfloat16(val);
  }
}

// ======================= mega kernel + fallback wrappers =======================
__global__ __launch_bounds__(256, 4) void mega(MArgs a) {
  __shared__ __align__(16) float sm[8192];
  bool f32 = detect_f32(a.x);
  int blk = blockIdx.x, tid = threadIdx.x;
  cg::grid_group grid = cg::this_grid();
  stage1(a, sm, f32, blk, tid);
  grid.sync();
  stage2(a, sm, f32, blk, tid);
  grid.sync();
  stage3(a, sm, f32, blk, tid);
  grid.sync();
  stage4(a, sm, f32, blk, tid);
}

__global__ __launch_bounds__(256, 4) void gs1(MArgs a) {
  __shared__ __align__(16) float sm[8192];
  stage1(a, sm, detect_f32(a.x), blockIdx.x, threadIdx.x);
}
__global__ __launch_bounds__(256, 4) void gs2(MArgs a) {
  __shared__ __align__(16) float sm[8192];
  stage2(a, sm, detect_f32(a.x), blockIdx.x, threadIdx.x);
}
__global__ __launch_bounds__(256, 4) void gs3(MArgs a) {
  __shared__ __align__(16) float sm[8192];
  stage3(a, sm, detect_f32(a.x), blockIdx.x, threadIdx.x);
}
__global__ __launch_bounds__(256, 4) void gs4(MArgs a) {
  __shared__ __align__(16) float sm[8192];
  stage4(a, sm, detect_f32(a.x), blockIdx.x, threadIdx.x);
}

extern "C" void kernel_launch(void* const* d_in, const int* in_sizes, int n_in,
                              void* d_out, int out_size, void* d_ws, size_t ws_size,
                              hipStream_t stream) {
  float* W = (float*)d_ws;
  MArgs a;
  a.x = d_in[0];   a.emb = d_in[1];  a.dec_w = d_in[2]; a.dec_b = d_in[3];
  a.w1 = d_in[4];  a.b1 = d_in[5];   a.w2 = d_in[6];    a.b2 = d_in[7];
  a.w3 = d_in[8];  a.b3 = d_in[9];
  a.cWq = d_in[10]; a.cWk = d_in[11]; a.cWv = d_in[12]; a.cWo = d_in[13];
  a.tWq = d_in[14]; a.tWk = d_in[15]; a.tWv = d_in[16]; a.tWo = d_in[17];
  a.drw = d_in[18]; a.drb = d_in[19]; a.out_w = d_in[20]; a.out_b = d_in[21];
  a.wfuse = d_in[22];
  a.res = W;    W += (size_t)CB * CT * CN;
  a.trend = W;  W += (size_t)CB * CT * CN;
  a.trendo = W; W += (size_t)CB * CN * CP;
  a.Pbuf = W;   W += (size_t)CB * CT * CH * CN;
  a.Qbuf = W;   W += (size_t)CB * CN * CG * CH * 2;
  a.ch = W;     W += 8;
  a.ewo = W;    W += CH * CD;
  a.ewq = W;    W += CH * CD;
  a.ewk = W;    W += CH * CD;
  a.ewv = W;    W += CH * CD;
  a.wod = W;    W += CD;
  a.owr = W;    W += CG * CP;
  a.owi = W;    W += CG * CP;
  a.gC = W;     W += 512;
  a.gU = W;     W += 64;
  a.out = d_out;

  void* kargs[] = { &a };
  hipError_t err = hipLaunchCooperativeKernel(reinterpret_cast<void*>(mega),
                                              dim3(1024), dim3(256), kargs, 0, stream);
  if (err != hipSuccess) {
    // fallback: same stage bodies as 4 regular launches
    gs1<<<1024, 256, 0, stream>>>(a);
    gs2<<<1024, 256, 0, stream>>>(a);
    gs3<<<1024, 256, 0, stream>>>(a);
    gs4<<<1024, 256, 0, stream>>>(a);
  }
}

// Round 8
// 210.070 us; speedup vs baseline: 2.7801x; 2.7801x over previous
//
#include <hip/hip_runtime.h>
#include <hip/hip_bf16.h>

typedef __hip_bfloat16 bf16;

constexpr int CB = 8;     // batch
constexpr int CT = 512;   // T
constexpr int CN = 64;    // N
constexpr int CD = 128;   // D
constexpr int CP = 96;    // PRED
constexpr int CH = 8;     // HEADS
constexpr int CDH = 16;   // head dim
constexpr int CHID = 256; // HID
constexpr int CM = 32;    // CEM freq tokens
constexpr int CG = 64;    // TEM freq tokens
constexpr float TWO_PI = 6.28318530717958647692f;

__device__ __forceinline__ float LD(const void* p, size_t i, bool f) {
  return f ? ((const float*)p)[i] : __bfloat162float(((const bf16*)p)[i]);
}
template <bool F32>
__device__ __forceinline__ float LDT(const void* p, size_t i) {
  return F32 ? ((const float*)p)[i] : __bfloat162float(((const bf16*)p)[i]);
}

__device__ __forceinline__ bool detect_f32(const void* x) {
  const unsigned int* xw = (const unsigned int*)x;
  unsigned int w = xw[threadIdx.x & 63];
  unsigned int e = (w >> 7) & 0xFF;
  unsigned long long m = __ballot(e >= 0x90 || e <= 0x60);
  return __popcll(m) > 3;
}

__device__ __forceinline__ float2 pkfma(float2 a, float2 b, float2 c) {
  return make_float2(fmaf(a.x, b.x, c.x), fmaf(a.y, b.y, c.y));
}

struct MArgs {
  const void *x, *dec_w, *dec_b, *out_w, *emb, *cWq, *cWk, *cWv, *cWo;
  const void *tWq, *tWk, *tWv, *tWo, *drw, *drb, *out_b, *wfuse;
  const void *w1, *b1, *w2, *b2, *w3, *b3;
  float *trendo, *Pbuf, *ewq, *ewk, *ewv, *wod, *owr, *owi;
  void* out;
};

// ================= S2: k2+trend [0,128) | k3+res+ch [128,1152) | k_ow [1152,1216)
// ================= | k0b self-sufficient [1216,1228) | wod [1228] =================
template <bool F32>
__device__ void k2_body(float* sm, const MArgs& a) {
  // regions: xbuf [0,2560) (pad 5), rows [2560,4608), h1 [4608,5632), h2 [5632,6656)
  float* xbuf = sm;
  float* rows = sm + 2560;
  float* h1 = sm + 4608;
  float* h2 = sm + 5632;
  int r0 = blockIdx.x * 4;
  int b = r0 >> 6, n0 = r0 & 63;
  int tid = threadIdx.x;
  size_t xb = (size_t)b * CT * CN + n0;
  for (int i = tid; i < CT * 4; i += 256) {
    int t = i >> 2, q = i & 3;
    xbuf[t * 5 + q] = LDT<F32>(a.x, xb + (size_t)t * CN + q);
  }
  __syncthreads();
  // inline trend: sliding-window moving averages per (q, 8-t strip)
  {
    float w0 = LDT<F32>(a.dec_w, 0), w1 = LDT<F32>(a.dec_w, 1);
    float c0 = LDT<F32>(a.dec_b, 0), c1 = LDT<F32>(a.dec_b, 1);
    int q = tid & 3, tl = tid >> 2;
    int t0 = tl * 8;
    float s17 = 0.f, s49 = 0.f;
    #pragma unroll
    for (int o = -8; o <= 8; ++o) {
      int u = t0 + o; u = u < 0 ? 0 : (u > CT - 1 ? CT - 1 : u);
      s17 += xbuf[u * 5 + q];
    }
    #pragma unroll
    for (int o = -24; o <= 24; ++o) {
      int u = t0 + o; u = u < 0 ? 0 : (u > CT - 1 ? CT - 1 : u);
      s49 += xbuf[u * 5 + q];
    }
    #pragma unroll
    for (int k = 0; k < 8; ++k) {
      int t = t0 + k;
      if (k > 0) {
        int up8 = t + 8 > CT - 1 ? CT - 1 : t + 8;
        int dn9 = t - 9 < 0 ? 0 : t - 9;
        int up24 = t + 24 > CT - 1 ? CT - 1 : t + 24;
        int dn25 = t - 25 < 0 ? 0 : t - 25;
        s17 += xbuf[up8 * 5 + q] - xbuf[dn9 * 5 + q];
        s49 += xbuf[up24 * 5 + q] - xbuf[dn25 * 5 + q];
      }
      float m0 = s17 * (1.f / 17.f), m1 = s49 * (1.f / 49.f);
      float xv = xbuf[t * 5 + q];
      float l0 = xv * w0 + c0, l1 = xv * w1 + c1;
      float mx = fmaxf(l0, l1);
      float e0 = __expf(l0 - mx), e1 = __expf(l1 - mx);
      rows[q * CT + t] = (e0 * m0 + e1 * m1) / (e0 + e1);
    }
  }
  __syncthreads();
  int c = tid;
  float a0, a1, a2, a3;
  {
    float bias = LDT<F32>(a.b1, c);
    a0 = a1 = a2 = a3 = 0.f;
    #pragma unroll 16
    for (int t = 0; t < CT; ++t) {
      float w = LDT<F32>(a.w1, t * CHID + c);
      a0 += rows[0 * CT + t] * w; a1 += rows[1 * CT + t] * w;
      a2 += rows[2 * CT + t] * w; a3 += rows[3 * CT + t] * w;
    }
    h1[0 * CHID + c] = fmaxf(a0 + bias, 0.f); h1[1 * CHID + c] = fmaxf(a1 + bias, 0.f);
    h1[2 * CHID + c] = fmaxf(a2 + bias, 0.f); h1[3 * CHID + c] = fmaxf(a3 + bias, 0.f);
  }
  __syncthreads();
  {
    float bias = LDT<F32>(a.b2, c);
    a0 = a1 = a2 = a3 = 0.f;
    #pragma unroll 16
    for (int i = 0; i < CHID; ++i) {
      float w = LDT<F32>(a.w2, i * CHID + c);
      a0 += h1[0 * CHID + i] * w; a1 += h1[1 * CHID + i] * w;
      a2 += h1[2 * CHID + i] * w; a3 += h1[3 * CHID + i] * w;
    }
    h2[0 * CHID + c] = fmaxf(a0 + bias, 0.f); h2[1 * CHID + c] = fmaxf(a1 + bias, 0.f);
    h2[2 * CHID + c] = fmaxf(a2 + bias, 0.f); h2[3 * CHID + c] = fmaxf(a3 + bias, 0.f);
  }
  __syncthreads();
  if (tid < 2 * CP) {
    int p = tid < CP ? tid : tid - CP;
    int qh = tid < CP ? 0 : 2;
    float bias = LDT<F32>(a.b3, p);
    a0 = a1 = 0.f;
    #pragma unroll 16
    for (int i = 0; i < CHID; ++i) {
      float w = LDT<F32>(a.w3, i * CP + p);
      a0 += h2[qh * CHID + i] * w; a1 += h2[(qh + 1) * CHID + i] * w;
    }
    a.trendo[((size_t)(b * CN + n0 + qh)) * CP + p] = a0 + bias;
    a.trendo[((size_t)(b * CN + n0 + qh + 1)) * CP + p] = a1 + bias;
  }
}

__global__ __launch_bounds__(256, 4) void kS2(MArgs a) {
  __shared__ __align__(16) float sm[6656];
  bool f32 = detect_f32(a.x);
  int blk = blockIdx.x, tid = threadIdx.x;
  if (blk < 128) {
    if (f32) k2_body<true>(sm, a);
    else     k2_body<false>(sm, a);
  } else if (blk < 1152) {
    // ---- k3: inline res + CEM collapsed attention, 4 t per block (1/wave) ----
    float* xl = sm;            // [52][64]
    float* rowl = sm + 3328;   // [4][64] residuals
    float* Rr = sm + 3584;     // [4][32]
    float* Ri = sm + 3712;
    float* aR = sm + 3840;
    float* Sr = sm + 3968;     // [4][256]
    float* Si = sm + 4992;
    float* chtmp = sm + 6016;  // [128]
    float* chl = sm + 6144;    // [8]
    float* eml = sm + 6152;    // [128]
    int bk = blk - 128;
    int b = bk >> 7, tbase = (bk & 127) * 4;
    int w = tid >> 6, lane = tid & 63;
    // load x halo tile rows [tbase-24, tbase+27] clamped
    size_t xb = (size_t)b * CT * CN;
    for (int i = tid; i < 52 * 64; i += 256) {
      int r = i >> 6, n = i & 63;
      int u = tbase - 24 + r; u = u < 0 ? 0 : (u > CT - 1 ? CT - 1 : u);
      xl[i] = LD(a.x, xb + (size_t)u * CN + n, f32);
    }
    if (tid < 128) eml[tid] = LD(a.emb, tid, f32);
    __syncthreads();
    // ch[h] = |sum_j (emb@cWq)[h*16+j] * (emb@cWk)[h*16+j]|
    if (tid < 128) {
      float pq = 0, pk = 0;
      #pragma unroll 8
      for (int d = 0; d < CD; ++d) {
        float em = eml[d];
        pq += em * LD(a.cWq, d * CD + tid, f32);
        pk += em * LD(a.cWk, d * CD + tid, f32);
      }
      chtmp[tid] = pq * pk;
    }
    __syncthreads();
    if (tid < CH) {
      float s = 0;
      #pragma unroll
      for (int j = 0; j < 16; ++j) s += chtmp[tid * 16 + j];
      chl[tid] = fabsf(s);
    }
    // inline residual for this wave's t
    {
      int t = tbase + w;
      int Lt = 24 + w;
      float w0 = LD(a.dec_w, 0, f32), w1 = LD(a.dec_w, 1, f32);
      float c0 = LD(a.dec_b, 0, f32), c1 = LD(a.dec_b, 1, f32);
      float s17 = 0;
      #pragma unroll
      for (int o = -8; o <= 8; ++o) s17 += xl[(Lt + o) * 64 + lane];
      float s49 = 0;
      #pragma unroll
      for (int o = -24; o <= 24; ++o) s49 += xl[(Lt + o) * 64 + lane];
      float m0 = s17 * (1.f / 17.f), m1 = s49 * (1.f / 49.f);
      float xv = xl[Lt * 64 + lane];
      float l0 = xv * w0 + c0, l1 = xv * w1 + c1;
      float mx = fmaxf(l0, l1);
      float e0 = __expf(l0 - mx), e1 = __expf(l1 - mx);
      float tr = (e0 * m0 + e1 * m1) / (e0 + e1);
      rowl[w * 64 + lane] = xv - tr;
      (void)t;
    }
    __syncthreads();
    // R-DFT (f = lane < 32), phasor recurrence; rowl reads are wave-uniform broadcast
    if (lane < CM) {
      float cf, sf;
      sincosf((float)lane * (TWO_PI / CN), &sf, &cf);
      float wr = 1.f, wi = 0.f, rr = 0.f, ri = 0.f;
      #pragma unroll 8
      for (int n2 = 0; n2 < CN; ++n2) {
        float xv = rowl[w * 64 + n2];
        rr = fmaf(xv, wr, rr); ri = fmaf(-xv, wi, ri);
        float nr = wr * cf - wi * sf; wi = wi * cf + wr * sf; wr = nr;
      }
      Rr[w * 32 + lane] = rr; Ri[w * 32 + lane] = ri;
      aR[w * 32 + lane] = sqrtf(rr * rr + ri * ri);
    }
    __syncthreads();
    float amax = 0;
    for (int m = 0; m < CM; ++m) amax = fmaxf(amax, aR[w * 32 + m]);
    #pragma unroll
    for (int i = 0; i < 4; ++i) {
      int pair = lane + 64 * i;
      int h = pair >> 5, m = pair & 31;
      float alpha = 0.25f * chl[h] * aR[w * 32 + m];
      float den = 0, sr = 0, si = 0;
      for (int n2 = 0; n2 < CM; ++n2) {
        float e = __expf(alpha * (aR[w * 32 + n2] - amax));
        den += e; sr += e * Rr[w * 32 + n2]; si += e * Ri[w * 32 + n2];
      }
      Sr[w * 256 + pair] = sr / den; Si[w * 256 + pair] = si / den;
    }
    __syncthreads();
    // irfft (n = lane), phasor recurrence; Sr/Si reads are wave-uniform broadcast
    {
      int n2 = lane, t = tbase + w;
      float acc[8];
      #pragma unroll
      for (int h = 0; h < CH; ++h) acc[h] = Sr[w * 256 + h * 32]; // f=0, Re only
      float cd, sd;
      sincosf((float)n2 * (TWO_PI / CN), &sd, &cd);
      float px = cd, py = sd;
      for (int f = 1; f < CM; ++f) {
        #pragma unroll
        for (int h = 0; h < CH; ++h)
          acc[h] += 2.f * (Sr[w * 256 + h * 32 + f] * px - Si[w * 256 + h * 32 + f] * py);
        float nx = px * cd - py * sd; py = py * cd + px * sd; px = nx;
      }
      float* Pb = a.Pbuf + (((size_t)(b * CN + n2)) * CT + t) * CH;
      ((float4*)Pb)[0] = make_float4(acc[0] * (1.f / CN), acc[1] * (1.f / CN),
                                     acc[2] * (1.f / CN), acc[3] * (1.f / CN));
      ((float4*)Pb)[1] = make_float4(acc[4] * (1.f / CN), acc[5] * (1.f / CN),
                                     acc[6] * (1.f / CN), acc[7] * (1.f / CN));
    }
  } else if (blk < 1216) {
    // ---- k_ow: phasor recurrence, 2 t-halves, LDS partial reduce ----
    float* ps = sm; // [2][96][2]
    int g = blk - 1152;
    int tc = tid >> 7, idx = tid & 127;
    if (idx < CP) {
      int p = idx, t0 = tc * 256;
      float s0, c0v, ss, cs;
      sincosf((float)((g * t0) & (CT - 1)) * (TWO_PI / CT), &s0, &c0v);
      sincosf((float)g * (TWO_PI / CT), &ss, &cs);
      float wr = c0v, wi = s0, ar = 0.f, ai = 0.f;
      #pragma unroll 16
      for (int t = 0; t < 256; ++t) {
        float w = LD(a.out_w, (size_t)(t0 + t) * CP + p, f32);
        ar = fmaf(w, wr, ar); ai = fmaf(w, wi, ai);
        float nr = wr * cs - wi * ss; wi = wi * cs + wr * ss; wr = nr;
      }
      ps[(tc * CP + p) * 2] = ar; ps[(tc * CP + p) * 2 + 1] = ai;
    }
    __syncthreads();
    if (tid < CP) {
      a.owr[g * CP + tid] = ps[tid * 2] + ps[(CP + tid) * 2];
      a.owi[g * CP + tid] = ps[tid * 2 + 1] + ps[(CP + tid) * 2 + 1];
    }
  } else if (blk < 1228) {
    // ---- k0b self-sufficient: recompute evl slice + ewo row, then project ----
    float* eml = sm;           // [128]
    float* evl = sm + 128;     // [2][16]
    float* ewoh = sm + 160;    // [2][128]
    int bi = blk - 1216;
    int half = tid >> 7, e = tid & 127;
    int pairIdx = bi * 2 + half;
    int which = pairIdx >> 3, h = pairIdx & 7;
    if (tid < 128) eml[tid] = LD(a.emb, tid, f32);
    __syncthreads();
    if (e < 16) {
      float acc = 0;
      #pragma unroll 8
      for (int d = 0; d < CD; ++d) acc += eml[d] * LD(a.cWv, d * CD + h * CDH + e, f32);
      evl[half * 16 + e] = acc;
    }
    __syncthreads();
    {
      float acc = 0;
      #pragma unroll
      for (int j = 0; j < CDH; ++j)
        acc += evl[half * 16 + j] * LD(a.cWo, (h * CDH + j) * CD + e, f32);
      ewoh[half * 128 + e] = acc;
    }
    __syncthreads();
    {
      const void* W = which == 0 ? a.tWq : (which == 1 ? a.tWk : a.tWv);
      float acc = 0;
      #pragma unroll 8
      for (int d = 0; d < CD; ++d) acc += ewoh[half * 128 + d] * LD(W, d * CD + e, f32);
      (which == 0 ? a.ewq : (which == 1 ? a.ewk : a.ewv))[h * CD + e] = acc;
    }
  } else {
    // ---- wod[e] = tWo[e,:] . drw ----
    float* drl = sm;
    if (tid < 128) drl[tid] = LD(a.drw, tid, f32);
    __syncthreads();
    if (tid < 128) {
      float acc = 0;
      #pragma unroll 8
      for (int d = 0; d < CD; ++d) acc += LD(a.tWo, tid * CD + d, f32) * drl[d];
      a.wod[tid] = acc;
    }
  }
}

// ================= S3: fused k4-DFT + C/u + k5 attention + epilogue, 512 blocks ==========
__global__ __launch_bounds__(256, 4) void kS3(MArgs a) {
  __shared__ __align__(16) float sm[7872];
  float* Pl = sm;                        // [512][8]
  float* QL = sm + 4096;                 // [64][16]
  float* Cl = sm + 5120;                 // [512]
  float* Ul = sm + 5632;                 // [64]
  float2* vdL = (float2*)(sm + 5696);    // [8][64]
  float2* zL = (float2*)(sm + 6720);     // [8][64]
  float* zrow = sm + 7744;               // [64][2]
  bool f32 = detect_f32(a.x);
  int blk = blockIdx.x, tid = threadIdx.x;
  int b = blk >> 6, n = blk & 63;
  const float4* Pp4 = (const float4*)(a.Pbuf + ((size_t)(b * CN + n)) * CT * CH);
  float4* Pl4 = (float4*)Pl;
  for (int i = tid; i < CT * CH / 4; i += 256) Pl4[i] = Pp4[i];
  // inline C_h (8x8) and u_h per block
  for (int id = tid; id < 512 + 64; id += 256) {
    if (id < 512) {
      int h = id >> 6, aa = (id >> 3) & 7, b2 = id & 7;
      float c = 0;
      #pragma unroll
      for (int j = 0; j < CDH; ++j)
        c += a.ewq[aa * CD + h * CDH + j] * a.ewk[b2 * CD + h * CDH + j];
      Cl[id] = c;
    } else {
      int r = id - 512;
      int h = r >> 3, aa = r & 7;
      float c = 0;
      #pragma unroll
      for (int j = 0; j < CDH; ++j) c += a.ewv[aa * CD + h * CDH + j] * a.wod[h * CDH + j];
      Ul[r] = c;
    }
  }
  __syncthreads();
  // k4: dual-g phasor DFT into QL
  {
    int g1 = tid >> 3, h = tid & 7, g2 = g1 + 32;
    float s1, c1, s2, c2;
    sincosf((float)g1 * (TWO_PI / CT), &s1, &c1);
    sincosf((float)g2 * (TWO_PI / CT), &s2, &c2);
    float wr1 = 1.f, wi1 = 0.f, wr2 = 1.f, wi2 = 0.f;
    float r1 = 0, i1 = 0, r2 = 0, i2 = 0;
    #pragma unroll 8
    for (int t = 0; t < CT; ++t) {
      float p = Pl[t * CH + h];
      r1 += p * wr1; i1 += p * wi1;
      r2 += p * wr2; i2 += p * wi2;
      float nr1 = wr1 * c1 + wi1 * s1; wi1 = wi1 * c1 - wr1 * s1; wr1 = nr1;
      float nr2 = wr2 * c2 + wi2 * s2; wi2 = wi2 * c2 - wr2 * s2; wr2 = nr2;
    }
    QL[g1 * 16 + h * 2] = r1; QL[g1 * 16 + h * 2 + 1] = i1;
    QL[g2 * 16 + h * 2] = r2; QL[g2 * 16 + h * 2 + 1] = i2;
  }
  __syncthreads();
  // k5: rank-8 attention, 4 waves x (2 heads each), online softmax
  int h0 = tid >> 6, m = tid & 63;
  float2 qp[8];
  {
    const float4* q4 = (const float4*)(QL + m * 16);
    #pragma unroll
    for (int j = 0; j < 4; ++j) {
      float4 y = q4[j];
      qp[2 * j] = make_float2(y.x, y.y);
      qp[2 * j + 1] = make_float2(y.z, y.w);
    }
  }
  #pragma unroll
  for (int e2 = 0; e2 < 2; ++e2) {
    int hh = h0 + e2 * 4;
    float vr = 0, vi = 0;
    #pragma unroll
    for (int aa = 0; aa < 8; ++aa) {
      float u = Ul[hh * 8 + aa];
      vr += qp[aa].x * u; vi += qp[aa].y * u;
    }
    vdL[hh * 64 + m] = make_float2(vr, vi);
  }
  __syncthreads();
  for (int e2 = 0; e2 < 2; ++e2) {
    int hh = h0 + e2 * 4;
    float2 uu[8], vv[8];
    #pragma unroll
    for (int bb = 0; bb < 8; ++bb) {
      float sr = 0, si = 0;
      #pragma unroll
      for (int aa = 0; aa < 8; ++aa) {
        float c = Cl[(hh * 8 + aa) * 8 + bb];
        sr += qp[aa].x * c; si += qp[aa].y * c;
      }
      uu[bb] = make_float2(sr, si);
      vv[bb] = make_float2(si, -sr);
    }
    float mx = -1e30f, den = 0.f, zr = 0.f, zi = 0.f;
    #pragma unroll 4
    for (int g = 0; g < CG; ++g) {
      const float4* k4p = (const float4*)(QL + g * 16);
      float2 sr2 = make_float2(0.f, 0.f), si2 = make_float2(0.f, 0.f);
      #pragma unroll
      for (int j = 0; j < 4; ++j) {
        float4 y = k4p[j];
        float2 y0 = make_float2(y.x, y.y), y1 = make_float2(y.z, y.w);
        sr2 = pkfma(uu[2 * j], y0, sr2); si2 = pkfma(vv[2 * j], y0, si2);
        sr2 = pkfma(uu[2 * j + 1], y1, sr2); si2 = pkfma(vv[2 * j + 1], y1, si2);
      }
      float sr = sr2.x + sr2.y;
      float si = si2.x + si2.y;
      float s = 0.25f * sqrtf(sr * sr + si * si);
      if (s > mx) {
        float f = __expf(mx - s);
        den *= f; zr *= f; zi *= f; mx = s;
      }
      float e = __expf(s - mx);
      float2 vd = vdL[hh * 64 + g];
      den += e; zr += e * vd.x; zi += e * vd.y;
    }
    float rv = 1.f / den;
    zL[hh * 64 + m] = make_float2(zr * rv, zi * rv);
  }
  __syncthreads();
  if (tid < 128) {
    int g = tid >> 1, c = tid & 1;
    float acc = 0;
    #pragma unroll
    for (int hh = 0; hh < CH; ++hh) acc += c ? zL[hh * 64 + g].y : zL[hh * 64 + g].x;
    zrow[g * 2 + c] = acc;
  }
  __syncthreads();
  if (tid < CP) {
    int p = tid;
    float acc = zrow[0] * a.owr[p] - zrow[1] * a.owi[p]; // g=0 (bin-0 imag dropped)
    #pragma unroll 8
    for (int g = 1; g < CG; ++g)
      acc += 2.f * (zrow[g * 2] * a.owr[g * CP + p] - zrow[g * 2 + 1] * a.owi[g * CP + p]);
    float xo = acc * (1.f / CT) + LD(a.drb, 0, f32) * a.owr[p] + LD(a.out_b, p, f32);
    float val = LD(a.wfuse, 0, f32) * xo
              + LD(a.wfuse, 1, f32) * a.trendo[((size_t)(b * CN + n)) * CP + p];
    size_t oidx = ((size_t)(b * CP + p)) * CN + n;
    if (f32) ((float*)a.out)[oidx] = val;
    else ((bf16*)a.out)[oidx] = __float2bfloat16(val);
  }
}

extern "C" void kernel_launch(void* const* d_in, const int* in_sizes, int n_in,
                              void* d_out, int out_size, void* d_ws, size_t ws_size,
                              hipStream_t stream) {
  float* W = (float*)d_ws;
  MArgs a;
  a.x = d_in[0];   a.emb = d_in[1];  a.dec_w = d_in[2]; a.dec_b = d_in[3];
  a.w1 = d_in[4];  a.b1 = d_in[5];   a.w2 = d_in[6];    a.b2 = d_in[7];
  a.w3 = d_in[8];  a.b3 = d_in[9];
  a.cWq = d_in[10]; a.cWk = d_in[11]; a.cWv = d_in[12]; a.cWo = d_in[13];
  a.tWq = d_in[14]; a.tWk = d_in[15]; a.tWv = d_in[16]; a.tWo = d_in[17];
  a.drw = d_in[18]; a.drb = d_in[19]; a.out_w = d_in[20]; a.out_b = d_in[21];
  a.wfuse = d_in[22];
  a.trendo = W; W += (size_t)CB * CN * CP;
  a.Pbuf = W;   W += (size_t)CB * CN * CT * CH;
  a.ewq = W;    W += CH * CD;
  a.ewk = W;    W += CH * CD;
  a.ewv = W;    W += CH * CD;
  a.wod = W;    W += CD;
  a.owr = W;    W += CG * CP;
  a.owi = W;    W += CG * CP;
  a.out = d_out;

  kS2<<<1229, 256, 0, stream>>>(a);
  kS3<<<512, 256, 0, stream>>>(a);
}